// Round 3
// baseline (126.680 us; speedup 1.0000x reference)
//
#include <hip/hip_runtime.h>
#include <math.h>

#define NS2 0.70710678118654752440f  // 1/sqrt(2)
#define NS3 0.57735026918962576451f  // 1/sqrt(3)
#define NS6 0.40824829046386301636f  // 1/sqrt(6)

// ws layout (float offsets), weight rows padded to 8 floats (32B) for dwordx4 loads
#define OFF_G0   0        // [5120][8]   G0[c][k]  = sum_o W3_0[c,o] * Wout[o,k]
#define OFF_K1A  40960    // [3][2048][8] K1a[m][c][k] = sum_o W3_1[c,o]*Wout[64+o*3+m,k]
#define OFF_K1B  90112    // [3][2048][8] K1b[m][c][k] = sum_o W3_1[2048+c,o]*Wout[64+o*3+m,k]
#define OFF_K2   139264   // [5][1024][8] K2[m][c][k]  = sum_o W3_2[c,o]*Wout[160+o*5+m,k]
#define OFF_FEAT 180224   // [N/8 groups][208 rows][8 nodes]  (rows: a0 0-63, b0 64-127,
                          //  A1 128-159, B1 160-191, geom 192-200, pad to 208)
#define FEAT_STRIDE 1664  // 208*8 floats per group

__global__ __launch_bounds__(256) void precompute_kernel(
    const float* __restrict__ W3_0, const float* __restrict__ W3_1,
    const float* __restrict__ W3_2, const float* __restrict__ Wout,
    float* __restrict__ ws)
{
    __shared__ float s_wo[1680];           // Wout is 240x7
    for (int i = threadIdx.x; i < 1680; i += 256) s_wo[i] = Wout[i];
    __syncthreads();

    int row = blockIdx.x * 256 + threadIdx.x;
    if (row >= 22528) return;
    float acc[7] = {0.f,0.f,0.f,0.f,0.f,0.f,0.f};
    float* dst;
    if (row < 5120) {
        const float* wr = W3_0 + row * 64;
        #pragma unroll 4
        for (int o = 0; o < 64; o += 4) {
            float4 wv = *(const float4*)(wr + o);
            const float* w0 = s_wo + o * 7;
            #pragma unroll
            for (int k = 0; k < 7; ++k)
                acc[k] = fmaf(wv.x, w0[k],
                         fmaf(wv.y, w0[7+k],
                         fmaf(wv.z, w0[14+k],
                         fmaf(wv.w, w0[21+k], acc[k]))));
        }
        dst = ws + OFF_G0 + row * 8;
    } else if (row < 11264) {
        int t = row - 5120, m = t >> 11, c = t & 2047;
        const float* wr = W3_1 + c * 32;
        #pragma unroll 4
        for (int o = 0; o < 32; o += 4) {
            float4 wv = *(const float4*)(wr + o);
            const float* w0 = s_wo + (64 + o*3 + m) * 7;
            #pragma unroll
            for (int k = 0; k < 7; ++k)
                acc[k] = fmaf(wv.x, w0[k],
                         fmaf(wv.y, w0[21+k],
                         fmaf(wv.z, w0[42+k],
                         fmaf(wv.w, w0[63+k], acc[k]))));
        }
        dst = ws + OFF_K1A + t * 8;
    } else if (row < 17408) {
        int t = row - 11264, m = t >> 11, c = t & 2047;
        const float* wr = W3_1 + (2048 + c) * 32;
        #pragma unroll 4
        for (int o = 0; o < 32; o += 4) {
            float4 wv = *(const float4*)(wr + o);
            const float* w0 = s_wo + (64 + o*3 + m) * 7;
            #pragma unroll
            for (int k = 0; k < 7; ++k)
                acc[k] = fmaf(wv.x, w0[k],
                         fmaf(wv.y, w0[21+k],
                         fmaf(wv.z, w0[42+k],
                         fmaf(wv.w, w0[63+k], acc[k]))));
        }
        dst = ws + OFF_K1B + t * 8;
    } else {
        int t = row - 17408, m = t >> 10, c = t & 1023;
        const float* wr = W3_2 + c * 16;
        #pragma unroll 4
        for (int o = 0; o < 16; o += 4) {
            float4 wv = *(const float4*)(wr + o);
            const float* w0 = s_wo + (160 + o*5 + m) * 7;
            #pragma unroll
            for (int k = 0; k < 7; ++k)
                acc[k] = fmaf(wv.x, w0[k],
                         fmaf(wv.y, w0[35+k],
                         fmaf(wv.z, w0[70+k],
                         fmaf(wv.w, w0[105+k], acc[k]))));
        }
        dst = ws + OFF_K2 + t * 8;
    }
    *(float4*)dst       = make_float4(acc[0], acc[1], acc[2], acc[3]);
    *(float4*)(dst + 4) = make_float4(acc[4], acc[5], acc[6], 0.f);
}

// One block = 8 nodes: basis, matvecs, geometry -> ws feature table; also out = bias.
__global__ __launch_bounds__(256) void feature_kernel(
    const float* __restrict__ pos,
    const float* __restrict__ W1_0, const float* __restrict__ W1_1,
    const float* __restrict__ W2_0, const float* __restrict__ W2_1,
    const float* __restrict__ bout,
    float* __restrict__ ws, float* __restrict__ out, int N)
{
    __shared__ float s_f0[8][64];
    __shared__ float s_f1[8][32];

    const int tid  = threadIdx.x;
    const int base = blockIdx.x * 8;
    float* feat = ws + OFF_FEAT + (size_t)blockIdx.x * FEAT_STRIDE;

    {
        int d = tid & 63;
        #pragma unroll
        for (int jj = 0; jj < 2; ++jj) {
            int j = (tid >> 6) + jj * 4;
            int n = base + j;
            float px = pos[n*3+0], py = pos[n*3+1], pz = pos[n*3+2];
            float r  = sqrtf(px*px + py*py + pz*pz) + 1e-9f;
            float t0 = r - (5.0f/63.0f) * (float)d;
            s_f0[j][d] = __expf(-4.f * t0 * t0);
        }
        {
            int j = tid >> 5, d1 = tid & 31;
            int n = base + j;
            float px = pos[n*3+0], py = pos[n*3+1], pz = pos[n*3+2];
            float r  = sqrtf(px*px + py*py + pz*pz) + 1e-9f;
            float t1 = r - (5.0f/31.0f) * (float)d1;
            s_f1[j][d1] = __expf(-4.f * t1 * t1);
        }
        if (tid < 8) {
            int n = base + tid;
            float px = pos[n*3+0], py = pos[n*3+1], pz = pos[n*3+2];
            float r  = sqrtf(px*px + py*py + pz*pz) + 1e-9f;
            float iv = 1.0f / r;
            float d0 = py*iv, d1 = pz*iv, d2 = px*iv;       // (y,z,x)
            feat[(192+0)*8 + tid] = d0;
            feat[(192+1)*8 + tid] = d1;
            feat[(192+2)*8 + tid] = d2;
            feat[(192+3)*8 + tid] = NS3 * (d0*d0 + d1*d1 + d2*d2);
            feat[(192+4)*8 + tid] = 2.f*NS2*d2*d0;
            feat[(192+5)*8 + tid] = 2.f*NS2*d0*d1;
            feat[(192+6)*8 + tid] = NS6*(2.f*d1*d1 - d2*d2 - d0*d0);
            feat[(192+7)*8 + tid] = 2.f*NS2*d2*d1;
            feat[(192+8)*8 + tid] = NS2*(d2*d2 - d0*d0);
        }
        if (tid < 56) out[base*7 + tid] = bout[tid % 7];
    }
    __syncthreads();

    {
        int c = tid & 63, jb = tid >> 6;
        float aa0 = 0.f, aa1 = 0.f, ba0 = 0.f, ba1 = 0.f;
        const float* wa = W1_0 + c;
        const float* wb = W2_0 + c;
        #pragma unroll 4
        for (int d = 0; d < 64; ++d) {
            float wav = wa[d*64], wbv = wb[d*64];
            float fA = s_f0[jb][d], fB = s_f0[jb+4][d];
            aa0 = fmaf(fA, wav, aa0);  aa1 = fmaf(fB, wav, aa1);
            ba0 = fmaf(fA, wbv, ba0);  ba1 = fmaf(fB, wbv, ba1);
        }
        feat[c*8 + jb]        = aa0;  feat[c*8 + jb + 4]        = aa1;
        feat[(64+c)*8 + jb]   = ba0;  feat[(64+c)*8 + jb + 4]   = ba1;

        int c1 = tid & 31, j8 = tid >> 5;
        float aA = 0.f, aB = 0.f;
        const float* wA = W1_1 + c1;
        const float* wB = W2_1 + c1;
        #pragma unroll 4
        for (int d = 0; d < 32; ++d) {
            float f = s_f1[j8][d];
            aA = fmaf(f, wA[d*32], aA);
            aB = fmaf(f, wB[d*32], aB);
        }
        feat[(128+c1)*8 + j8] = aA;
        feat[(160+c1)*8 + j8] = aB;
    }
}

__device__ __forceinline__ void accum8(float acc[8][7],
                                       const float* __restrict__ av8,  // LDS row, 8 floats (broadcast)
                                       const float rb[8],
                                       const float* __restrict__ row)  // weight row, 8 floats (per-lane)
{
    float4 gA = *(const float4*)row;
    float4 gB = *(const float4*)(row + 4);
    float g[7] = {gA.x, gA.y, gA.z, gA.w, gB.x, gB.y, gB.z};
    float4 a0v = *(const float4*)av8;
    float4 a1v = *(const float4*)(av8 + 4);
    float av[8] = {a0v.x, a0v.y, a0v.z, a0v.w, a1v.x, a1v.y, a1v.z, a1v.w};
    #pragma unroll
    for (int j = 0; j < 8; ++j) {
        float p = av[j] * rb[j];
        #pragma unroll
        for (int k = 0; k < 7; ++k) acc[j][k] = fmaf(p, g[k], acc[j][k]);
    }
}

// grid = (N/8)*2 blocks; block (g, cs): 8 nodes of group g, channel-half cs.
// 4 waves per block split each half 4 ways. Partials atomicAdd'ed into out.
__global__ __launch_bounds__(256) void main_kernel(
    const float* __restrict__ ws, float* __restrict__ out, int N)
{
    __shared__ float s_feat[FEAT_STRIDE];
    __shared__ float s_red[4][56];

    const int tid  = threadIdx.x;
    const int w    = tid >> 6;
    const int lane = tid & 63;
    const int g    = blockIdx.x >> 1;
    const int cs   = blockIdx.x & 1;
    const int base = g * 8;

    // ---- stage features (6.5 KB, coalesced float4) ----
    {
        const float4* src = (const float4*)(ws + OFF_FEAT + (size_t)g * FEAT_STRIDE);
        float4* dst = (float4*)s_feat;
        #pragma unroll
        for (int i = tid; i < FEAT_STRIDE/4; i += 256) dst[i] = src[i];
    }
    __syncthreads();

    const int bh = lane & 31, ah = lane >> 5;
    float b0r[8], B1r[8];
    {
        float4 t0 = *(const float4*)&s_feat[(64+lane)*8];
        float4 t1 = *(const float4*)&s_feat[(64+lane)*8 + 4];
        b0r[0]=t0.x; b0r[1]=t0.y; b0r[2]=t0.z; b0r[3]=t0.w;
        b0r[4]=t1.x; b0r[5]=t1.y; b0r[6]=t1.z; b0r[7]=t1.w;
        float4 u0 = *(const float4*)&s_feat[(160+bh)*8];
        float4 u1 = *(const float4*)&s_feat[(160+bh)*8 + 4];
        B1r[0]=u0.x; B1r[1]=u0.y; B1r[2]=u0.z; B1r[3]=u0.w;
        B1r[4]=u1.x; B1r[5]=u1.y; B1r[6]=u1.z; B1r[7]=u1.w;
    }
    const float* s_geom = s_feat + 192*8;   // [m][8]

    float acc[8][7];
    #pragma unroll
    for (int j = 0; j < 8; ++j)
        #pragma unroll
        for (int k = 0; k < 7; ++k) acc[j][k] = 0.f;

    // ---- P1: 0x0->0, b = lane, a = w*16 + cs*8 + i ----
    {
        const float* sec = ws + OFF_G0;
        #pragma unroll 2
        for (int i = 0; i < 8; ++i) {
            int a = w*16 + cs*8 + i;
            accum8(acc, &s_feat[a*8], b0r, sec + (a*64 + lane)*8);
        }
    }
    // ---- P2: 1x1->0, b = bh, a = ah*16 + w*4 + cs*2 + i ----
    {
        float rb[8];
        #pragma unroll
        for (int j = 0; j < 8; ++j) rb[j] = B1r[j] * s_geom[3*8 + j];
        const float* sec = ws + OFF_G0 + 4096*8;
        #pragma unroll
        for (int i = 0; i < 2; ++i) {
            int a = ah*16 + w*4 + cs*2 + i;
            accum8(acc, &s_feat[(128+a)*8], rb, sec + (a*32 + bh)*8);
        }
    }
    // ---- P3: 0x1->1 (K1a), a = ah*32 + w*8 + cs*4 + i ----
    #pragma unroll
    for (int m = 0; m < 3; ++m) {
        float rb[8];
        #pragma unroll
        for (int j = 0; j < 8; ++j) rb[j] = B1r[j] * s_geom[m*8 + j];
        const float* sec = ws + OFF_K1A + m*2048*8;
        #pragma unroll 2
        for (int i = 0; i < 4; ++i) {
            int a = ah*32 + w*8 + cs*4 + i;
            accum8(acc, &s_feat[a*8], rb, sec + (a*32 + bh)*8);
        }
    }
    // ---- P4: 1x0->1 (K1b), b = lane, a = w*8 + cs*4 + i ----
    #pragma unroll
    for (int m = 0; m < 3; ++m) {
        float rb[8];
        #pragma unroll
        for (int j = 0; j < 8; ++j) rb[j] = b0r[j] * s_geom[m*8 + j];
        const float* sec = ws + OFF_K1B + m*2048*8;
        #pragma unroll 2
        for (int i = 0; i < 4; ++i) {
            int a = w*8 + cs*4 + i;
            accum8(acc, &s_feat[(128+a)*8], rb, sec + (a*64 + lane)*8);
        }
    }
    // ---- P5: 1x1->2 (K2), a = ah*16 + w*4 + cs*2 + i ----
    #pragma unroll
    for (int m = 0; m < 5; ++m) {
        float rb[8];
        #pragma unroll
        for (int j = 0; j < 8; ++j) rb[j] = B1r[j] * s_geom[(4+m)*8 + j];
        const float* sec = ws + OFF_K2 + m*1024*8;
        #pragma unroll
        for (int i = 0; i < 2; ++i) {
            int a = ah*16 + w*4 + cs*2 + i;
            accum8(acc, &s_feat[(128+a)*8], rb, sec + (a*32 + bh)*8);
        }
    }

    // ---- reduce across 64 lanes, across 4 waves, then atomic into out ----
    #pragma unroll
    for (int j = 0; j < 8; ++j)
        #pragma unroll
        for (int k = 0; k < 7; ++k) {
            float v = acc[j][k];
            v += __shfl_xor(v, 1, 64);
            v += __shfl_xor(v, 2, 64);
            v += __shfl_xor(v, 4, 64);
            v += __shfl_xor(v, 8, 64);
            v += __shfl_xor(v, 16, 64);
            v += __shfl_xor(v, 32, 64);
            acc[j][k] = v;
        }
    if (lane == 0) {
        #pragma unroll
        for (int j = 0; j < 8; ++j)
            #pragma unroll
            for (int k = 0; k < 7; ++k)
                s_red[w][j*7 + k] = acc[j][k];
    }
    __syncthreads();
    if (tid < 56) {
        float v = s_red[0][tid] + s_red[1][tid] + s_red[2][tid] + s_red[3][tid];
        atomicAdd(&out[base*7 + tid], v);
    }
}

extern "C" void kernel_launch(void* const* d_in, const int* in_sizes, int n_in,
                              void* d_out, int out_size, void* d_ws, size_t ws_size,
                              hipStream_t stream)
{
    const float* pos  = (const float*)d_in[0];
    const float* W1_0 = (const float*)d_in[1];
    const float* W1_1 = (const float*)d_in[2];
    const float* W2_0 = (const float*)d_in[3];
    const float* W2_1 = (const float*)d_in[4];
    const float* W3_0 = (const float*)d_in[5];
    const float* W3_1 = (const float*)d_in[6];
    const float* W3_2 = (const float*)d_in[7];
    const float* Wout = (const float*)d_in[8];
    const float* bout = (const float*)d_in[9];
    float* ws  = (float*)d_ws;
    float* op  = (float*)d_out;
    int N = in_sizes[0] / 3;   // 4096

    precompute_kernel<<<88, 256, 0, stream>>>(W3_0, W3_1, W3_2, Wout, ws);
    feature_kernel<<<N / 8, 256, 0, stream>>>(pos, W1_0, W1_1, W2_0, W2_1, bout, ws, op, N);
    main_kernel<<<(N / 8) * 2, 256, 0, stream>>>(ws, op, N);
}